// Round 5
// baseline (1266.088 us; speedup 1.0000x reference)
//
#include <hip/hip_runtime.h>
#include <hip/hip_bf16.h>
#include <hip/hip_fp16.h>

#define NB 4
#define LL 4096
#define SS 4096
#define CC 128

typedef unsigned short u16;
typedef _Float16 f16;
typedef __attribute__((ext_vector_type(8))) short  short8;
typedef __attribute__((ext_vector_type(8))) f16    f16x8;
typedef __attribute__((ext_vector_type(4))) float  f32x4;
typedef __attribute__((ext_vector_type(4))) u16    u16x4;

// ---------- helpers ----------
__device__ __forceinline__ u16 f2bf(float f) {
  unsigned u = __float_as_uint(f);
  return (u16)((u + 0x7FFFu + ((u >> 16) & 1u)) >> 16);   // RNE, inputs finite
}

__device__ __forceinline__ void gload_lds16(const void* g, void* l) {
  __builtin_amdgcn_global_load_lds(
      (const __attribute__((address_space(1))) unsigned*)g,
      (__attribute__((address_space(3))) unsigned*)l, 16, 0, 0);
}

template <int NW>
__device__ __forceinline__ float block_sum(float v, float* red, int t) {
#pragma unroll
  for (int m = 1; m < 64; m <<= 1) v += __shfl_xor(v, m, 64);
  if ((t & 63) == 0) red[t >> 6] = v;
  __syncthreads();
  float s = 0.f;
#pragma unroll
  for (int w = 0; w < NW; ++w) s += red[w];
  __syncthreads();
  return s;
}

// ---------- fp32 -> bf16 conversion ----------
__global__ __launch_bounds__(256) void k_convert(const float* __restrict__ f0,
                                                 const float* __restrict__ f1,
                                                 u16* __restrict__ b0,
                                                 u16* __restrict__ b1) {
  const int i = blockIdx.x * 256 + threadIdx.x;
  const int n = NB * LL * CC / 4;
  if (i >= n) return;
  f32x4 x = ((const f32x4*)f0)[i];
  f32x4 y = ((const f32x4*)f1)[i];
  u16x4 a, c;
  a[0] = f2bf(x[0]); a[1] = f2bf(x[1]); a[2] = f2bf(x[2]); a[3] = f2bf(x[3]);
  c[0] = f2bf(y[0]); c[1] = f2bf(y[1]); c[2] = f2bf(y[2]); c[3] = f2bf(y[3]);
  ((u16x4*)b0)[i] = a;
  ((u16x4*)b1)[i] = c;
}

// ---------- bf16 MFMA GEMM: E = exp(f0.f1^T/128) f16, fused rowsum, LDS-restaged stores ----------
__global__ __launch_bounds__(256) void k_gemm(const u16* __restrict__ b0,
                                              const u16* __restrict__ b1,
                                              f16* __restrict__ E,
                                              float* __restrict__ rowacc) {
  __shared__ u16 smem[2 * 128 * 128];
  u16* lA = smem;
  u16* lB = smem + 128 * 128;
  const int bx = blockIdx.x, by = blockIdx.y, bz = blockIdx.z;
  const int tid = threadIdx.x;
  const int lane = tid & 63, wave = tid >> 6;

  const u16* gA = b0 + (size_t)bz * LL * CC + (size_t)by * 128 * CC;
  const u16* gB = b1 + (size_t)bz * SS * CC + (size_t)bx * 128 * CC;

#pragma unroll
  for (int i = 0; i < 8; ++i) {
    const int c = i * 256 + tid;
    const int row = c >> 4;
    const int slot = c & 15;
    const int kchunk = slot ^ (row & 7);
    const size_t soff = (size_t)row * CC + kchunk * 8;
    const int ldsoff = (i * 256 + wave * 64) * 16;
    gload_lds16(gA + soff, (char*)lA + ldsoff);
    gload_lds16(gB + soff, (char*)lB + ldsoff);
  }
  __syncthreads();

  const int wr = wave >> 1, wc = wave & 1;
  f32x4 acc[4][4];
#pragma unroll
  for (int i = 0; i < 4; ++i)
#pragma unroll
    for (int j = 0; j < 4; ++j) acc[i][j] = (f32x4){0.f, 0.f, 0.f, 0.f};

#pragma unroll
  for (int ks = 0; ks < 4; ++ks) {
    short8 af[4], bfr[4];
#pragma unroll
    for (int mi = 0; mi < 4; ++mi) {
      const int row = wr * 64 + mi * 16 + (lane & 15);
      const int kc = ks * 4 + (lane >> 4);
      af[mi] = *(const short8*)&lA[row * 128 + (kc ^ (row & 7)) * 8];
    }
#pragma unroll
    for (int ni = 0; ni < 4; ++ni) {
      const int row = wc * 64 + ni * 16 + (lane & 15);
      const int kc = ks * 4 + (lane >> 4);
      bfr[ni] = *(const short8*)&lB[row * 128 + (kc ^ (row & 7)) * 8];
    }
#pragma unroll
    for (int mi = 0; mi < 4; ++mi)
#pragma unroll
      for (int ni = 0; ni < 4; ++ni)
        acc[mi][ni] = __builtin_amdgcn_mfma_f32_16x16x32_bf16(af[mi], bfr[ni], acc[mi][ni], 0, 0, 0);
  }

  __syncthreads();                       // all LDS fragment reads done
  f16* st = (f16*)smem;                  // staging, row stride 136 f16 (16B-aligned rows)
  const float scale = 1.0f / 128.0f;
#pragma unroll
  for (int mi = 0; mi < 4; ++mi) {
    float rs[4] = {0.f, 0.f, 0.f, 0.f};
    const int lr0 = wr * 64 + mi * 16 + (lane >> 4) * 4;
#pragma unroll
    for (int ni = 0; ni < 4; ++ni) {
      const int lc = wc * 64 + ni * 16 + (lane & 15);
      f32x4 a = acc[mi][ni];
#pragma unroll
      for (int r = 0; r < 4; ++r) {
        const f16 eh = (f16)__expf(a[r] * scale);
        st[(lr0 + r) * 136 + lc] = eh;
        rs[r] += (float)eh;
      }
    }
#pragma unroll
    for (int m = 1; m < 16; m <<= 1)
#pragma unroll
      for (int r = 0; r < 4; ++r) rs[r] += __shfl_xor(rs[r], m, 64);
    if ((lane & 15) == 0) {
#pragma unroll
      for (int r = 0; r < 4; ++r)
        atomicAdd(&rowacc[bz * LL + by * 128 + lr0 + r], rs[r]);
    }
  }
  __syncthreads();
  const size_t ebase = (size_t)bz * LL * SS + (size_t)(by * 128) * SS + (size_t)(bx * 128);
#pragma unroll
  for (int i = 0; i < 8; ++i) {
    const int c = i * 256 + tid;
    const int row = c >> 4, c16 = c & 15;
    f16x8 vv = *(const f16x8*)&st[row * 136 + c16 * 8];
    *(f16x8*)&E[ebase + (size_t)row * SS + c16 * 8] = vv;
  }
}

// ---------- iter-1 column pass: eu1 from rowacc; colacc1 += eu1*E. 16-row strips, 256 thr ----------
__global__ __launch_bounds__(256) void k_col1(const f16* __restrict__ E,
                                              const float* __restrict__ rowacc,
                                              float* __restrict__ c1g,
                                              const float* __restrict__ alpha_p) {
  __shared__ float eu_lds[16];
  const int b = blockIdx.y, strip = blockIdx.x, t = threadIdx.x;
  const float EA = __expf(*alpha_p);
  const float enorm = 1.0f / 8192.0f;
  if (t < 16) eu_lds[t] = enorm / (rowacc[(size_t)b * LL + strip * 16 + t] + EA);
  __syncthreads();
  const f16* Eb = E + (size_t)b * LL * SS + (size_t)strip * 16 * SS;
  float acc[16];
#pragma unroll
  for (int e = 0; e < 16; ++e) acc[e] = 0.f;
  for (int r = 0; r < 16; ++r) {
    const f16x8 h0 = *(const f16x8*)(Eb + (size_t)r * SS + t * 16);
    const f16x8 h1 = *(const f16x8*)(Eb + (size_t)r * SS + t * 16 + 8);
    const float eu = eu_lds[r];
#pragma unroll
    for (int e = 0; e < 8; ++e) acc[e] += eu * (float)h0[e];
#pragma unroll
    for (int e = 0; e < 8; ++e) acc[8 + e] += eu * (float)h1[e];
  }
  float* co = c1g + (size_t)b * SS;
#pragma unroll
  for (int e = 0; e < 16; ++e) atomicAdd(&co[t * 16 + e], acc[e]);
}

// ---------- fused Sinkhorn iteration (2 or 3), 16-row strips, 256 thr, prefetched rows ----------
template <int ITER>
__global__ __launch_bounds__(256) void k_iter(const f16* __restrict__ E,
                                              const float* __restrict__ rowacc,
                                              const float* __restrict__ c1g,
                                              const float* __restrict__ cing,
                                              float* __restrict__ coutg,
                                              float* __restrict__ eu3g,
                                              float* __restrict__ s2g,
                                              const float* __restrict__ alpha_p) {
  __shared__ float ev_lds[4096];
  __shared__ float red[4];
  __shared__ float redr[8];
  const int b = blockIdx.y, strip = blockIdx.x;
  const int t = threadIdx.x, lane = t & 63, wave = t >> 6;
  const float alpha = *alpha_p;
  const float EA = __expf(alpha), HE = 0.5f * __expf(-alpha);
  const float enorm = 1.0f / 8192.0f;
  const float EU1BIN = HE / 4097.0f, BTV1 = 0.5f / 4097.0f;
  const float* ra = rowacc + (size_t)b * LL;
  const float* c1 = c1g + (size_t)b * SS;
  const float* ci = cing + (size_t)b * SS;

  float p1 = 0.f, p2 = 0.f;
  if (ITER == 2) {
    for (int i = t; i < 4096; i += 256) {
      const float e1 = enorm / (ci[i] + BTV1);   // ev1
      ev_lds[i] = e1;
      p1 += e1;
      p2 += enorm / (ra[i] + EA);                // eu1
    }
  } else {
    for (int i = t; i < 4096; i += 256) {
      p1 += enorm / (c1[i] + BTV1);              // ev1 (sum only)
      p2 += enorm / (ra[i] + EA);                // eu1
    }
  }
  const float sev1 = block_sum<4>(p1, red, t);
  const float sa1 = block_sum<4>(p2, red, t);
  const float ev1bin = HE / (sa1 + EU1BIN);
  float btu;
  if (ITER == 2) {
    btu = EA * ev1bin;
  } else {
    const float eu2bin = HE / (sev1 + ev1bin);
    const float btv2 = EA * eu2bin;
    for (int i = t; i < 4096; i += 256) ev_lds[i] = enorm / (ci[i] + btv2);  // ev2
    const float ev2bin = HE / (s2g[b] + eu2bin);
    btu = EA * ev2bin;
    __syncthreads();
  }

  // this thread's 16-column ev slice in registers
  const f32x4 evA = *(const f32x4*)&ev_lds[t * 16];
  const f32x4 evB = *(const f32x4*)&ev_lds[t * 16 + 4];
  const f32x4 evC = *(const f32x4*)&ev_lds[t * 16 + 8];
  const f32x4 evD = *(const f32x4*)&ev_lds[t * 16 + 12];

  const f16* Eb = E + (size_t)b * LL * SS + (size_t)strip * 16 * SS;
  float acc[16];
#pragma unroll
  for (int e = 0; e < 16; ++e) acc[e] = 0.f;
  float seu = 0.f;

  f16x8 h0 = *(const f16x8*)(Eb + t * 16);
  f16x8 h1 = *(const f16x8*)(Eb + t * 16 + 8);
#pragma unroll
  for (int r = 0; r < 16; ++r) {
    f16x8 n0, n1;
    if (r < 15) {                                  // prefetch next row BEFORE the barrier
      n0 = *(const f16x8*)(Eb + (size_t)(r + 1) * SS + t * 16);
      n1 = *(const f16x8*)(Eb + (size_t)(r + 1) * SS + t * 16 + 8);
    }
    float d = 0.f;
#pragma unroll
    for (int e = 0; e < 4; ++e) d += (float)h0[e] * evA[e];
#pragma unroll
    for (int e = 0; e < 4; ++e) d += (float)h0[4 + e] * evB[e];
#pragma unroll
    for (int e = 0; e < 4; ++e) d += (float)h1[e] * evC[e];
#pragma unroll
    for (int e = 0; e < 4; ++e) d += (float)h1[4 + e] * evD[e];
#pragma unroll
    for (int m = 1; m < 64; m <<= 1) d += __shfl_xor(d, m, 64);
    if (lane == 0) redr[(r & 1) * 4 + wave] = d;
    __syncthreads();
    float rowdot = redr[(r & 1) * 4 + 0] + redr[(r & 1) * 4 + 1] +
                   redr[(r & 1) * 4 + 2] + redr[(r & 1) * 4 + 3];
    const float eu = enorm / (rowdot + btu);
    if (ITER == 3 && t == 0) eu3g[(size_t)b * LL + strip * 16 + r] = eu;
    if (ITER == 2) seu += eu;
#pragma unroll
    for (int e = 0; e < 8; ++e) acc[e] += eu * (float)h0[e];
#pragma unroll
    for (int e = 0; e < 8; ++e) acc[8 + e] += eu * (float)h1[e];
    h0 = n0;
    h1 = n1;
  }

  float* co = coutg + (size_t)b * SS;
#pragma unroll
  for (int e = 0; e < 16; ++e) atomicAdd(&co[t * 16 + e], acc[e]);
  if (ITER == 2 && t == 0) atomicAdd(&s2g[b], seu * (1.0f / 16.0f) * 16.0f);  // seu summed once per block
}

// ---------- final: ev3 from colacc3 (register slice), out = E*eu3[l]*ev3[s]*8192 ----------
__global__ __launch_bounds__(256) void k_finalize(const f16* __restrict__ E,
                                                  float* __restrict__ out,
                                                  const float* __restrict__ rowacc,
                                                  const float* __restrict__ c1g,
                                                  const float* __restrict__ c2g,
                                                  const float* __restrict__ c3g,
                                                  const float* __restrict__ eu3g,
                                                  const float* __restrict__ s2g,
                                                  const float* __restrict__ alpha_p) {
  __shared__ float red[4];
  __shared__ float eu_s[16];
  const int b = blockIdx.y, rb = blockIdx.x;
  const int t = threadIdx.x, lane = t & 63, wave = t >> 6;
  const float alpha = *alpha_p;
  const float EA = __expf(alpha), HE = 0.5f * __expf(-alpha);
  const float enorm = 1.0f / 8192.0f;
  const float EU1BIN = HE / 4097.0f, BTV1 = 0.5f / 4097.0f;
  const float* ra = rowacc + (size_t)b * LL;
  const float* c1 = c1g + (size_t)b * SS;
  const float* c2 = c2g + (size_t)b * SS;
  const float* c3 = c3g + (size_t)b * SS;

  float p1 = 0.f, p2 = 0.f;
  for (int i = t; i < 4096; i += 256) {
    p1 += enorm / (c1[i] + BTV1);
    p2 += enorm / (ra[i] + EA);
  }
  const float sev1 = block_sum<4>(p1, red, t);
  const float sa1 = block_sum<4>(p2, red, t);
  const float ev1bin = HE / (sa1 + EU1BIN);
  const float eu2bin = HE / (sev1 + ev1bin);
  const float btv2 = EA * eu2bin;
  float p3 = 0.f;
  for (int i = t; i < 4096; i += 256) p3 += enorm / (c2[i] + btv2);
  const float sev2 = block_sum<4>(p3, red, t);
  const float ev2bin = HE / (s2g[b] + eu2bin);
  const float eu3bin = HE / (sev2 + ev2bin);
  const float btv3 = EA * eu3bin;

  if (t < 16) eu_s[t] = eu3g[(size_t)b * LL + rb * 16 + t] * 8192.0f;

  f32x4 evr[16];
#pragma unroll
  for (int it = 0; it < 8; ++it) {
    const int base = (it * 64 + lane) * 8;
    f32x4 q0 = *(const f32x4*)&c3[base];
    f32x4 q1 = *(const f32x4*)&c3[base + 4];
    f32x4 r0, r1;
#pragma unroll
    for (int e = 0; e < 4; ++e) { r0[e] = enorm / (q0[e] + btv3); r1[e] = enorm / (q1[e] + btv3); }
    evr[it * 2] = r0;
    evr[it * 2 + 1] = r1;
  }
  __syncthreads();

  const size_t rbase = (size_t)b * LL * SS + (size_t)(rb * 16) * SS;
#pragma unroll
  for (int rr = 0; rr < 4; ++rr) {
    const int rloc = wave * 4 + rr;
    const float a = eu_s[rloc];
    const f16x8* rowp = (const f16x8*)(E + rbase + (size_t)rloc * SS);
    f32x4* orow = (f32x4*)(out + rbase + (size_t)rloc * SS);
#pragma unroll
    for (int it = 0; it < 8; ++it) {
      const f16x8 h = rowp[it * 64 + lane];
      f32x4 o0, o1;
#pragma unroll
      for (int e = 0; e < 4; ++e) o0[e] = (float)h[e] * a * evr[it * 2][e];
#pragma unroll
      for (int e = 0; e < 4; ++e) o1[e] = (float)h[4 + e] * a * evr[it * 2 + 1][e];
      orow[2 * (it * 64 + lane)] = o0;
      orow[2 * (it * 64 + lane) + 1] = o1;
    }
  }
}

// ---------- launch ----------
extern "C" void kernel_launch(void* const* d_in, const int* in_sizes, int n_in,
                              void* d_out, int out_size, void* d_ws, size_t ws_size,
                              hipStream_t stream) {
  const float* f0 = (const float*)d_in[0];
  const float* f1 = (const float*)d_in[1];
  const float* alpha_p = (const float*)d_in[2];
  float* out = (float*)d_out;

  char* ws = (char*)d_ws;
  size_t off = (size_t)NB * LL * SS * 2;               // E: 128 MiB
  f16* E = (f16*)ws;
  u16* b0 = (u16*)(ws + off);  off += (size_t)NB * LL * CC * 2;
  u16* b1 = (u16*)(ws + off);  off += (size_t)NB * SS * CC * 2;
  float* rowacc = (float*)(ws + off); off += (size_t)NB * LL * 4;
  float* c1 = (float*)(ws + off);     off += (size_t)NB * SS * 4;
  float* c2 = (float*)(ws + off);     off += (size_t)NB * SS * 4;
  float* c3 = (float*)(ws + off);     off += (size_t)NB * SS * 4;
  float* s2 = (float*)(ws + off);     off += 256;
  float* eu3g = (float*)(ws + off);   off += (size_t)NB * LL * 4;

  // zero rowacc + c1 + c2 + c3 + s2 in one contiguous memset (every launch)
  hipMemsetAsync(rowacc, 0, (size_t)NB * (LL + 3 * SS) * 4 + 256, stream);

  k_convert<<<2048, 256, 0, stream>>>(f0, f1, b0, b1);
  k_gemm<<<dim3(SS / 128, LL / 128, NB), 256, 0, stream>>>(b0, b1, E, rowacc);
  k_col1<<<dim3(LL / 16, NB), 256, 0, stream>>>(E, rowacc, c1, alpha_p);
  k_iter<2><<<dim3(LL / 16, NB), 256, 0, stream>>>(E, rowacc, c1, c1, c2, eu3g, s2, alpha_p);
  k_iter<3><<<dim3(LL / 16, NB), 256, 0, stream>>>(E, rowacc, c1, c2, c3, eu3g, s2, alpha_p);
  k_finalize<<<dim3(LL / 16, NB), 256, 0, stream>>>(E, out, rowacc, c1, c2, c3, eu3g, s2, alpha_p);
}

// Round 6
// 762.039 us; speedup vs baseline: 1.6614x; 1.6614x over previous
//
#include <hip/hip_runtime.h>
#include <hip/hip_bf16.h>
#include <hip/hip_fp16.h>

#define NB 4
#define LL 4096
#define SS 4096
#define CC 128

typedef unsigned short u16;
typedef _Float16 f16;
typedef __attribute__((ext_vector_type(8))) short  short8;
typedef __attribute__((ext_vector_type(8))) f16    f16x8;
typedef __attribute__((ext_vector_type(4))) float  f32x4;
typedef __attribute__((ext_vector_type(4))) u16    u16x4;

// ---------- helpers ----------
__device__ __forceinline__ u16 f2bf(float f) {
  unsigned u = __float_as_uint(f);
  return (u16)((u + 0x7FFFu + ((u >> 16) & 1u)) >> 16);   // RNE, inputs finite
}

__device__ __forceinline__ void gload_lds16(const void* g, void* l) {
  __builtin_amdgcn_global_load_lds(
      (const __attribute__((address_space(1))) unsigned*)g,
      (__attribute__((address_space(3))) unsigned*)l, 16, 0, 0);
}

template <int NW>
__device__ __forceinline__ float block_sum(float v, float* red, int t) {
#pragma unroll
  for (int m = 1; m < 64; m <<= 1) v += __shfl_xor(v, m, 64);
  if ((t & 63) == 0) red[t >> 6] = v;
  __syncthreads();
  float s = 0.f;
#pragma unroll
  for (int w = 0; w < NW; ++w) s += red[w];
  __syncthreads();
  return s;
}

// ---------- fp32 -> bf16 conversion ----------
__global__ __launch_bounds__(256) void k_convert(const float* __restrict__ f0,
                                                 const float* __restrict__ f1,
                                                 u16* __restrict__ b0,
                                                 u16* __restrict__ b1) {
  const int i = blockIdx.x * 256 + threadIdx.x;
  const int n = NB * LL * CC / 4;
  if (i >= n) return;
  f32x4 x = ((const f32x4*)f0)[i];
  f32x4 y = ((const f32x4*)f1)[i];
  u16x4 a, c;
  a[0] = f2bf(x[0]); a[1] = f2bf(x[1]); a[2] = f2bf(x[2]); a[3] = f2bf(x[3]);
  c[0] = f2bf(y[0]); c[1] = f2bf(y[1]); c[2] = f2bf(y[2]); c[3] = f2bf(y[3]);
  ((u16x4*)b0)[i] = a;
  ((u16x4*)b1)[i] = c;
}

// ---------- bf16 MFMA GEMM: E = exp(f0.f1^T/128) f16, fused rowsum, LDS-restaged stores ----------
__global__ __launch_bounds__(256) void k_gemm(const u16* __restrict__ b0,
                                              const u16* __restrict__ b1,
                                              f16* __restrict__ E,
                                              float* __restrict__ rowacc) {
  __shared__ u16 smem[2 * 128 * 128];
  u16* lA = smem;
  u16* lB = smem + 128 * 128;
  const int bx = blockIdx.x, by = blockIdx.y, bz = blockIdx.z;
  const int tid = threadIdx.x;
  const int lane = tid & 63, wave = tid >> 6;

  const u16* gA = b0 + (size_t)bz * LL * CC + (size_t)by * 128 * CC;
  const u16* gB = b1 + (size_t)bz * SS * CC + (size_t)bx * 128 * CC;

#pragma unroll
  for (int i = 0; i < 8; ++i) {
    const int c = i * 256 + tid;
    const int row = c >> 4;
    const int slot = c & 15;
    const int kchunk = slot ^ (row & 7);
    const size_t soff = (size_t)row * CC + kchunk * 8;
    const int ldsoff = (i * 256 + wave * 64) * 16;
    gload_lds16(gA + soff, (char*)lA + ldsoff);
    gload_lds16(gB + soff, (char*)lB + ldsoff);
  }
  __syncthreads();

  const int wr = wave >> 1, wc = wave & 1;
  f32x4 acc[4][4];
#pragma unroll
  for (int i = 0; i < 4; ++i)
#pragma unroll
    for (int j = 0; j < 4; ++j) acc[i][j] = (f32x4){0.f, 0.f, 0.f, 0.f};

#pragma unroll
  for (int ks = 0; ks < 4; ++ks) {
    short8 af[4], bfr[4];
#pragma unroll
    for (int mi = 0; mi < 4; ++mi) {
      const int row = wr * 64 + mi * 16 + (lane & 15);
      const int kc = ks * 4 + (lane >> 4);
      af[mi] = *(const short8*)&lA[row * 128 + (kc ^ (row & 7)) * 8];
    }
#pragma unroll
    for (int ni = 0; ni < 4; ++ni) {
      const int row = wc * 64 + ni * 16 + (lane & 15);
      const int kc = ks * 4 + (lane >> 4);
      bfr[ni] = *(const short8*)&lB[row * 128 + (kc ^ (row & 7)) * 8];
    }
#pragma unroll
    for (int mi = 0; mi < 4; ++mi)
#pragma unroll
      for (int ni = 0; ni < 4; ++ni)
        acc[mi][ni] = __builtin_amdgcn_mfma_f32_16x16x32_bf16(af[mi], bfr[ni], acc[mi][ni], 0, 0, 0);
  }

  __syncthreads();                       // all LDS fragment reads done
  f16* st = (f16*)smem;                  // staging, row stride 136 f16 (16B-aligned rows)
  const float scale = 1.0f / 128.0f;
#pragma unroll
  for (int mi = 0; mi < 4; ++mi) {
    float rs[4] = {0.f, 0.f, 0.f, 0.f};
    const int lr0 = wr * 64 + mi * 16 + (lane >> 4) * 4;
#pragma unroll
    for (int ni = 0; ni < 4; ++ni) {
      const int lc = wc * 64 + ni * 16 + (lane & 15);
      f32x4 a = acc[mi][ni];
#pragma unroll
      for (int r = 0; r < 4; ++r) {
        const f16 eh = (f16)__expf(a[r] * scale);
        st[(lr0 + r) * 136 + lc] = eh;
        rs[r] += (float)eh;
      }
    }
#pragma unroll
    for (int m = 1; m < 16; m <<= 1)
#pragma unroll
      for (int r = 0; r < 4; ++r) rs[r] += __shfl_xor(rs[r], m, 64);
    if ((lane & 15) == 0) {
#pragma unroll
      for (int r = 0; r < 4; ++r)
        atomicAdd(&rowacc[bz * LL + by * 128 + lr0 + r], rs[r]);
    }
  }
  __syncthreads();
  const size_t ebase = (size_t)bz * LL * SS + (size_t)(by * 128) * SS + (size_t)(bx * 128);
#pragma unroll
  for (int i = 0; i < 8; ++i) {
    const int c = i * 256 + tid;
    const int row = c >> 4, c16 = c & 15;
    f16x8 vv = *(const f16x8*)&st[row * 136 + c16 * 8];
    *(f16x8*)&E[ebase + (size_t)row * SS + c16 * 8] = vv;
  }
}

// ---------- iter-1 column pass: eu1 from rowacc; colacc1 += eu1*E (barrier-free stream) ----------
__global__ __launch_bounds__(256) void k_col1(const f16* __restrict__ E,
                                              const float* __restrict__ rowacc,
                                              float* __restrict__ c1g,
                                              const float* __restrict__ alpha_p) {
  __shared__ float eu_lds[16];
  const int b = blockIdx.y, strip = blockIdx.x, t = threadIdx.x;
  const float EA = __expf(*alpha_p);
  const float enorm = 1.0f / 8192.0f;
  if (t < 16) eu_lds[t] = enorm / (rowacc[(size_t)b * LL + strip * 16 + t] + EA);
  __syncthreads();
  float eur[16];
#pragma unroll
  for (int r = 0; r < 16; ++r) eur[r] = eu_lds[r];

  const f16* Eb = E + (size_t)b * LL * SS + (size_t)strip * 16 * SS;
  const int cA = t * 8, cB = 2048 + t * 8;
  float accA[8], accB[8];
#pragma unroll
  for (int e = 0; e < 8; ++e) { accA[e] = 0.f; accB[e] = 0.f; }
#pragma unroll
  for (int r = 0; r < 16; ++r) {
    const f16x8 hA = *(const f16x8*)(Eb + (size_t)r * SS + cA);
    const f16x8 hB = *(const f16x8*)(Eb + (size_t)r * SS + cB);
#pragma unroll
    for (int e = 0; e < 8; ++e) { accA[e] += eur[r] * (float)hA[e]; accB[e] += eur[r] * (float)hB[e]; }
  }
  float* co = c1g + (size_t)b * SS;
#pragma unroll
  for (int e = 0; e < 8; ++e) atomicAdd(&co[cA + e], accA[e]);
#pragma unroll
  for (int e = 0; e < 8; ++e) atomicAdd(&co[cB + e], accB[e]);
}

// ---------- fused Sinkhorn iteration (2 or 3): 3-phase, no per-row barriers ----------
template <int ITER>
__global__ __launch_bounds__(256) void k_iter(const f16* __restrict__ E,
                                              const float* __restrict__ rowacc,
                                              const float* __restrict__ c1g,
                                              const float* __restrict__ c2g,
                                              float* __restrict__ coutg,
                                              float* __restrict__ eu3g,
                                              float* __restrict__ s2g,
                                              const float* __restrict__ alpha_p) {
  __shared__ float red[4];
  __shared__ float lds_red[4][16];
  __shared__ float eu_lds[16];
  const int b = blockIdx.y, strip = blockIdx.x;
  const int t = threadIdx.x, lane = t & 63, wave = t >> 6;
  const float alpha = *alpha_p;
  const float EA = __expf(alpha), HE = 0.5f * __expf(-alpha);
  const float enorm = 1.0f / 8192.0f;
  const float EU1BIN = HE / 4097.0f, BTV1 = 0.5f / 4097.0f;
  const float* ra = rowacc + (size_t)b * LL;
  const float* c1 = c1g + (size_t)b * SS;

  // scalar preamble: block-wide sums for the bin-chain
  float p2 = 0.f;
  for (int i = t; i < 4096; i += 256) p2 += enorm / (ra[i] + EA);
  const float sa1 = block_sum<4>(p2, red, t);
  const float ev1bin = HE / (sa1 + EU1BIN);
  float btu, btv;
  const float* cin;
  if (ITER == 2) {
    btu = EA * ev1bin;
    btv = BTV1;
    cin = c1;
  } else {
    float p1 = 0.f;
    for (int i = t; i < 4096; i += 256) p1 += enorm / (c1[i] + BTV1);
    const float sev1 = block_sum<4>(p1, red, t);
    const float eu2bin = HE / (sev1 + ev1bin);
    btv = EA * eu2bin;                              // for ev2
    const float ev2bin = HE / (s2g[b] + eu2bin);
    btu = EA * ev2bin;
    cin = c2g + (size_t)b * SS;
  }

  // own-column ev slice (8 + 8 split for perfect coalescing)
  const int cA = t * 8, cB = 2048 + t * 8;
  float evA[8], evB[8];
#pragma unroll
  for (int e = 0; e < 8; ++e) {
    evA[e] = enorm / (cin[cA + e] + btv);
    evB[e] = enorm / (cin[cB + e] + btv);
  }

  const f16* Eb = E + (size_t)b * LL * SS + (size_t)strip * 16 * SS;

  // ---- phase A: per-thread partial row-dots, barrier-free ----
  float partial[16];
#pragma unroll
  for (int r = 0; r < 16; ++r) {
    const f16x8 hA = *(const f16x8*)(Eb + (size_t)r * SS + cA);
    const f16x8 hB = *(const f16x8*)(Eb + (size_t)r * SS + cB);
    float d = 0.f;
#pragma unroll
    for (int e = 0; e < 8; ++e) d += (float)hA[e] * evA[e];
#pragma unroll
    for (int e = 0; e < 8; ++e) d += (float)hB[e] * evB[e];
    partial[r] = d;
  }

  // ---- phase B: reduce 16 rows across the block (independent butterflies) ----
#pragma unroll
  for (int m = 1; m < 64; m <<= 1)
#pragma unroll
    for (int r = 0; r < 16; ++r) partial[r] += __shfl_xor(partial[r], m, 64);
  if (lane == 0) {
#pragma unroll
    for (int r = 0; r < 16; ++r) lds_red[wave][r] = partial[r];
  }
  __syncthreads();
  if (t < 16) {
    const float rd = lds_red[0][t] + lds_red[1][t] + lds_red[2][t] + lds_red[3][t];
    const float eu = enorm / (rd + btu);
    eu_lds[t] = eu;
    if (ITER == 3) eu3g[(size_t)b * LL + strip * 16 + t] = eu;
  }
  __syncthreads();
  if (ITER == 2 && t == 0) {
    float s = 0.f;
#pragma unroll
    for (int r = 0; r < 16; ++r) s += eu_lds[r];
    atomicAdd(&s2g[b], s);
  }
  float eur[16];
#pragma unroll
  for (int r = 0; r < 16; ++r) eur[r] = eu_lds[r];

  // ---- phase C: colacc += eu[r] * E, re-read strip (L2/L3-hot), barrier-free ----
  float accA[8], accB[8];
#pragma unroll
  for (int e = 0; e < 8; ++e) { accA[e] = 0.f; accB[e] = 0.f; }
#pragma unroll
  for (int r = 0; r < 16; ++r) {
    const f16x8 hA = *(const f16x8*)(Eb + (size_t)r * SS + cA);
    const f16x8 hB = *(const f16x8*)(Eb + (size_t)r * SS + cB);
#pragma unroll
    for (int e = 0; e < 8; ++e) { accA[e] += eur[r] * (float)hA[e]; accB[e] += eur[r] * (float)hB[e]; }
  }
  float* co = coutg + (size_t)b * SS;
#pragma unroll
  for (int e = 0; e < 8; ++e) atomicAdd(&co[cA + e], accA[e]);
#pragma unroll
  for (int e = 0; e < 8; ++e) atomicAdd(&co[cB + e], accB[e]);
}

// ---------- final: ev3 from colacc3 (register slice), out = E*eu3[l]*ev3[s]*8192 ----------
__global__ __launch_bounds__(256) void k_finalize(const f16* __restrict__ E,
                                                  float* __restrict__ out,
                                                  const float* __restrict__ rowacc,
                                                  const float* __restrict__ c1g,
                                                  const float* __restrict__ c2g,
                                                  const float* __restrict__ c3g,
                                                  const float* __restrict__ eu3g,
                                                  const float* __restrict__ s2g,
                                                  const float* __restrict__ alpha_p) {
  __shared__ float red[4];
  __shared__ float eu_s[16];
  const int b = blockIdx.y, rb = blockIdx.x;
  const int t = threadIdx.x, lane = t & 63, wave = t >> 6;
  const float alpha = *alpha_p;
  const float EA = __expf(alpha), HE = 0.5f * __expf(-alpha);
  const float enorm = 1.0f / 8192.0f;
  const float EU1BIN = HE / 4097.0f, BTV1 = 0.5f / 4097.0f;
  const float* ra = rowacc + (size_t)b * LL;
  const float* c1 = c1g + (size_t)b * SS;
  const float* c2 = c2g + (size_t)b * SS;
  const float* c3 = c3g + (size_t)b * SS;

  float p1 = 0.f, p2 = 0.f;
  for (int i = t; i < 4096; i += 256) {
    p1 += enorm / (c1[i] + BTV1);
    p2 += enorm / (ra[i] + EA);
  }
  const float sev1 = block_sum<4>(p1, red, t);
  const float sa1 = block_sum<4>(p2, red, t);
  const float ev1bin = HE / (sa1 + EU1BIN);
  const float eu2bin = HE / (sev1 + ev1bin);
  const float btv2 = EA * eu2bin;
  float p3 = 0.f;
  for (int i = t; i < 4096; i += 256) p3 += enorm / (c2[i] + btv2);
  const float sev2 = block_sum<4>(p3, red, t);
  const float ev2bin = HE / (s2g[b] + eu2bin);
  const float eu3bin = HE / (sev2 + ev2bin);
  const float btv3 = EA * eu3bin;

  if (t < 16) eu_s[t] = eu3g[(size_t)b * LL + rb * 16 + t] * 8192.0f;

  f32x4 evr[16];
#pragma unroll
  for (int it = 0; it < 8; ++it) {
    const int base = (it * 64 + lane) * 8;
    f32x4 q0 = *(const f32x4*)&c3[base];
    f32x4 q1 = *(const f32x4*)&c3[base + 4];
    f32x4 r0, r1;
#pragma unroll
    for (int e = 0; e < 4; ++e) { r0[e] = enorm / (q0[e] + btv3); r1[e] = enorm / (q1[e] + btv3); }
    evr[it * 2] = r0;
    evr[it * 2 + 1] = r1;
  }
  __syncthreads();

  const size_t rbase = (size_t)b * LL * SS + (size_t)(rb * 16) * SS;
#pragma unroll
  for (int rr = 0; rr < 4; ++rr) {
    const int rloc = wave * 4 + rr;
    const float a = eu_s[rloc];
    const f16x8* rowp = (const f16x8*)(E + rbase + (size_t)rloc * SS);
    f32x4* orow = (f32x4*)(out + rbase + (size_t)rloc * SS);
#pragma unroll
    for (int it = 0; it < 8; ++it) {
      const f16x8 h = rowp[it * 64 + lane];
      f32x4 o0, o1;
#pragma unroll
      for (int e = 0; e < 4; ++e) o0[e] = (float)h[e] * a * evr[it * 2][e];
#pragma unroll
      for (int e = 0; e < 4; ++e) o1[e] = (float)h[4 + e] * a * evr[it * 2 + 1][e];
      orow[2 * (it * 64 + lane)] = o0;
      orow[2 * (it * 64 + lane) + 1] = o1;
    }
  }
}

// ---------- launch ----------
extern "C" void kernel_launch(void* const* d_in, const int* in_sizes, int n_in,
                              void* d_out, int out_size, void* d_ws, size_t ws_size,
                              hipStream_t stream) {
  const float* f0 = (const float*)d_in[0];
  const float* f1 = (const float*)d_in[1];
  const float* alpha_p = (const float*)d_in[2];
  float* out = (float*)d_out;

  char* ws = (char*)d_ws;
  size_t off = (size_t)NB * LL * SS * 2;               // E: 128 MiB
  f16* E = (f16*)ws;
  u16* b0 = (u16*)(ws + off);  off += (size_t)NB * LL * CC * 2;
  u16* b1 = (u16*)(ws + off);  off += (size_t)NB * SS * CC * 2;
  float* rowacc = (float*)(ws + off); off += (size_t)NB * LL * 4;
  float* c1 = (float*)(ws + off);     off += (size_t)NB * SS * 4;
  float* c2 = (float*)(ws + off);     off += (size_t)NB * SS * 4;
  float* c3 = (float*)(ws + off);     off += (size_t)NB * SS * 4;
  float* s2 = (float*)(ws + off);     off += 256;
  float* eu3g = (float*)(ws + off);   off += (size_t)NB * LL * 4;

  // zero rowacc + c1 + c2 + c3 + s2 in one contiguous memset (every launch)
  hipMemsetAsync(rowacc, 0, (size_t)NB * (LL + 3 * SS) * 4 + 256, stream);

  k_convert<<<2048, 256, 0, stream>>>(f0, f1, b0, b1);
  k_gemm<<<dim3(SS / 128, LL / 128, NB), 256, 0, stream>>>(b0, b1, E, rowacc);
  k_col1<<<dim3(LL / 16, NB), 256, 0, stream>>>(E, rowacc, c1, alpha_p);
  k_iter<2><<<dim3(LL / 16, NB), 256, 0, stream>>>(E, rowacc, c1, c2, c2, eu3g, s2, alpha_p);
  k_iter<3><<<dim3(LL / 16, NB), 256, 0, stream>>>(E, rowacc, c1, c2, c3, eu3g, s2, alpha_p);
  k_finalize<<<dim3(LL / 16, NB), 256, 0, stream>>>(E, out, rowacc, c1, c2, c3, eu3g, s2, alpha_p);
}

// Round 7
// 303.614 us; speedup vs baseline: 4.1701x; 2.5099x over previous
//
#include <hip/hip_runtime.h>
#include <hip/hip_bf16.h>
#include <hip/hip_fp16.h>

#define NB 4
#define LL 4096
#define SS 4096
#define CC 128
#define NSTRIP 256   // LL / 16

typedef unsigned short u16;
typedef _Float16 f16;
typedef __attribute__((ext_vector_type(8))) short  short8;
typedef __attribute__((ext_vector_type(8))) f16    f16x8;
typedef __attribute__((ext_vector_type(4))) float  f32x4;
typedef __attribute__((ext_vector_type(4))) u16    u16x4;

// ---------- helpers ----------
__device__ __forceinline__ u16 f2bf(float f) {
  unsigned u = __float_as_uint(f);
  return (u16)((u + 0x7FFFu + ((u >> 16) & 1u)) >> 16);   // RNE, inputs finite
}

__device__ __forceinline__ void gload_lds16(const void* g, void* l) {
  __builtin_amdgcn_global_load_lds(
      (const __attribute__((address_space(1))) unsigned*)g,
      (__attribute__((address_space(3))) unsigned*)l, 16, 0, 0);
}

template <int NW>
__device__ __forceinline__ float block_sum(float v, float* red, int t) {
#pragma unroll
  for (int m = 1; m < 64; m <<= 1) v += __shfl_xor(v, m, 64);
  if ((t & 63) == 0) red[t >> 6] = v;
  __syncthreads();
  float s = 0.f;
#pragma unroll
  for (int w = 0; w < NW; ++w) s += red[w];
  __syncthreads();
  return s;
}

// ---------- fp32 -> bf16 conversion ----------
__global__ __launch_bounds__(256) void k_convert(const float* __restrict__ f0,
                                                 const float* __restrict__ f1,
                                                 u16* __restrict__ b0,
                                                 u16* __restrict__ b1) {
  const int i = blockIdx.x * 256 + threadIdx.x;
  const int n = NB * LL * CC / 4;
  if (i >= n) return;
  f32x4 x = ((const f32x4*)f0)[i];
  f32x4 y = ((const f32x4*)f1)[i];
  u16x4 a, c;
  a[0] = f2bf(x[0]); a[1] = f2bf(x[1]); a[2] = f2bf(x[2]); a[3] = f2bf(x[3]);
  c[0] = f2bf(y[0]); c[1] = f2bf(y[1]); c[2] = f2bf(y[2]); c[3] = f2bf(y[3]);
  ((u16x4*)b0)[i] = a;
  ((u16x4*)b1)[i] = c;
}

// ---------- bf16 MFMA GEMM: E = exp(f0.f1^T/128) f16, partial rowsums (no atomics) ----------
__global__ __launch_bounds__(256) void k_gemm(const u16* __restrict__ b0,
                                              const u16* __restrict__ b1,
                                              f16* __restrict__ E,
                                              float* __restrict__ rowpart) {
  __shared__ u16 smem[2 * 128 * 128];
  u16* lA = smem;
  u16* lB = smem + 128 * 128;
  const int bx = blockIdx.x, by = blockIdx.y, bz = blockIdx.z;
  const int tid = threadIdx.x;
  const int lane = tid & 63, wave = tid >> 6;

  const u16* gA = b0 + (size_t)bz * LL * CC + (size_t)by * 128 * CC;
  const u16* gB = b1 + (size_t)bz * SS * CC + (size_t)bx * 128 * CC;

#pragma unroll
  for (int i = 0; i < 8; ++i) {
    const int c = i * 256 + tid;
    const int row = c >> 4;
    const int slot = c & 15;
    const int kchunk = slot ^ (row & 7);
    const size_t soff = (size_t)row * CC + kchunk * 8;
    const int ldsoff = (i * 256 + wave * 64) * 16;
    gload_lds16(gA + soff, (char*)lA + ldsoff);
    gload_lds16(gB + soff, (char*)lB + ldsoff);
  }
  __syncthreads();

  const int wr = wave >> 1, wc = wave & 1;
  f32x4 acc[4][4];
#pragma unroll
  for (int i = 0; i < 4; ++i)
#pragma unroll
    for (int j = 0; j < 4; ++j) acc[i][j] = (f32x4){0.f, 0.f, 0.f, 0.f};

#pragma unroll
  for (int ks = 0; ks < 4; ++ks) {
    short8 af[4], bfr[4];
#pragma unroll
    for (int mi = 0; mi < 4; ++mi) {
      const int row = wr * 64 + mi * 16 + (lane & 15);
      const int kc = ks * 4 + (lane >> 4);
      af[mi] = *(const short8*)&lA[row * 128 + (kc ^ (row & 7)) * 8];
    }
#pragma unroll
    for (int ni = 0; ni < 4; ++ni) {
      const int row = wc * 64 + ni * 16 + (lane & 15);
      const int kc = ks * 4 + (lane >> 4);
      bfr[ni] = *(const short8*)&lB[row * 128 + (kc ^ (row & 7)) * 8];
    }
#pragma unroll
    for (int mi = 0; mi < 4; ++mi)
#pragma unroll
      for (int ni = 0; ni < 4; ++ni)
        acc[mi][ni] = __builtin_amdgcn_mfma_f32_16x16x32_bf16(af[mi], bfr[ni], acc[mi][ni], 0, 0, 0);
  }

  __syncthreads();                       // all LDS fragment reads done
  f16* st = (f16*)smem;                  // staging, row stride 136 f16 (16B-aligned rows)
  const float scale = 1.0f / 128.0f;
  // rowpart slice: [bz][bx*2+wc][row]  (each wave's 64-col half-sum, no races)
  float* rp = rowpart + ((size_t)bz * 64 + bx * 2 + wc) * LL + by * 128;
#pragma unroll
  for (int mi = 0; mi < 4; ++mi) {
    float rs[4] = {0.f, 0.f, 0.f, 0.f};
    const int lr0 = wr * 64 + mi * 16 + (lane >> 4) * 4;
#pragma unroll
    for (int ni = 0; ni < 4; ++ni) {
      const int lc = wc * 64 + ni * 16 + (lane & 15);
      f32x4 a = acc[mi][ni];
#pragma unroll
      for (int r = 0; r < 4; ++r) {
        const f16 eh = (f16)__expf(a[r] * scale);
        st[(lr0 + r) * 136 + lc] = eh;
        rs[r] += (float)eh;
      }
    }
#pragma unroll
    for (int m = 1; m < 16; m <<= 1)
#pragma unroll
      for (int r = 0; r < 4; ++r) rs[r] += __shfl_xor(rs[r], m, 64);
    if ((lane & 15) == 0) {
#pragma unroll
      for (int r = 0; r < 4; ++r) rp[lr0 + r] = rs[r];
    }
  }
  __syncthreads();
  const size_t ebase = (size_t)bz * LL * SS + (size_t)(by * 128) * SS + (size_t)(bx * 128);
#pragma unroll
  for (int i = 0; i < 8; ++i) {
    const int c = i * 256 + tid;
    const int row = c >> 4, c16 = c & 15;
    f16x8 vv = *(const f16x8*)&st[row * 136 + c16 * 8];
    *(f16x8*)&E[ebase + (size_t)row * SS + c16 * 8] = vv;
  }
}

// ---------- reduce rowpart -> eu1, sa1 ----------
__global__ __launch_bounds__(1024) void k_redrow(const float* __restrict__ rowpart,
                                                 float* __restrict__ eu1g,
                                                 float* __restrict__ scal,
                                                 const float* __restrict__ alpha_p) {
  __shared__ float red[16];
  const int b = blockIdx.x, t = threadIdx.x;
  const float EA = __expf(*alpha_p);
  const float enorm = 1.0f / 8192.0f;
  float p = 0.f;
#pragma unroll
  for (int k = 0; k < 4; ++k) {
    const int l = t + k * 1024;
    float s = 0.f;
#pragma unroll 8
    for (int j = 0; j < 64; ++j) s += rowpart[((size_t)b * 64 + j) * LL + l];
    const float eu = enorm / (s + EA);
    eu1g[(size_t)b * LL + l] = eu;
    p += eu;
  }
  const float sa1 = block_sum<16>(p, red, t);
  if (t == 0) scal[b * 8 + 0] = sa1;
}

// ---------- column pass IT=1..3: (IT>1: row-dots -> eu), colpart[strip] = sum(eu*E) ----------
template <int IT>
__global__ __launch_bounds__(256) void k_colpass(const f16* __restrict__ E,
                                                 const float* __restrict__ eu1g,
                                                 const float* __restrict__ evprev,
                                                 float* __restrict__ colpart,
                                                 float* __restrict__ eu3g,
                                                 float* __restrict__ scal,
                                                 const float* __restrict__ alpha_p) {
  __shared__ float lds_red[4][16];
  __shared__ float eu_lds[16];
  const int b = blockIdx.y, strip = blockIdx.x;
  const int t = threadIdx.x, lane = t & 63, wave = t >> 6;
  const float alpha = *alpha_p;
  const float EA = __expf(alpha), HE = 0.5f * __expf(-alpha);
  const float enorm = 1.0f / 8192.0f;
  const float EU1BIN = HE / 4097.0f;

  const f16* Eb = E + (size_t)b * LL * SS + (size_t)strip * 16 * SS;
  const int cA = t * 8, cB = 2048 + t * 8;

  float eur[16];
  if (IT == 1) {
    const float* e1 = eu1g + (size_t)b * LL + strip * 16;
#pragma unroll
    for (int r = 0; r < 16; ++r) eur[r] = e1[r];
  } else {
    // bin-chain scalars from scal
    const float sa1 = scal[b * 8 + 0];
    const float ev1bin = HE / (sa1 + EU1BIN);
    float btu;
    if (IT == 2) {
      btu = EA * ev1bin;
    } else {
      const float sev1 = scal[b * 8 + 1];
      const float eu2bin = HE / (sev1 + ev1bin);
      const float s2 = scal[b * 8 + 2];
      const float ev2bin = HE / (s2 + eu2bin);
      btu = EA * ev2bin;
    }
    const float* evb = evprev + (size_t)b * SS;
    const f32x4 evA0 = *(const f32x4*)&evb[cA];
    const f32x4 evA1 = *(const f32x4*)&evb[cA + 4];
    const f32x4 evB0 = *(const f32x4*)&evb[cB];
    const f32x4 evB1 = *(const f32x4*)&evb[cB + 4];

    // phase A: per-thread partial row-dots (barrier-free)
    float partial[16];
#pragma unroll
    for (int r = 0; r < 16; ++r) {
      const f16x8 hA = *(const f16x8*)(Eb + (size_t)r * SS + cA);
      const f16x8 hB = *(const f16x8*)(Eb + (size_t)r * SS + cB);
      float d = 0.f;
#pragma unroll
      for (int e = 0; e < 4; ++e) d += (float)hA[e] * evA0[e];
#pragma unroll
      for (int e = 0; e < 4; ++e) d += (float)hA[4 + e] * evA1[e];
#pragma unroll
      for (int e = 0; e < 4; ++e) d += (float)hB[e] * evB0[e];
#pragma unroll
      for (int e = 0; e < 4; ++e) d += (float)hB[4 + e] * evB1[e];
      partial[r] = d;
    }
    // phase B: block reduction of 16 row-dots
#pragma unroll
    for (int m = 1; m < 64; m <<= 1)
#pragma unroll
      for (int r = 0; r < 16; ++r) partial[r] += __shfl_xor(partial[r], m, 64);
    if (lane == 0) {
#pragma unroll
      for (int r = 0; r < 16; ++r) lds_red[wave][r] = partial[r];
    }
    __syncthreads();
    if (t < 16) {
      const float rd = lds_red[0][t] + lds_red[1][t] + lds_red[2][t] + lds_red[3][t];
      const float eu = enorm / (rd + btu);
      eu_lds[t] = eu;
      if (IT == 3) eu3g[(size_t)b * LL + strip * 16 + t] = eu;
    }
    __syncthreads();
    if (IT == 2 && t == 0) {
      float s = 0.f;
#pragma unroll
      for (int r = 0; r < 16; ++r) s += eu_lds[r];
      atomicAdd(&scal[b * 8 + 2], s);
    }
#pragma unroll
    for (int r = 0; r < 16; ++r) eur[r] = eu_lds[r];
  }

  // phase C: colpart[strip] = sum(eu[r]*E) -- plain stores, no atomics
  float accA[8], accB[8];
#pragma unroll
  for (int e = 0; e < 8; ++e) { accA[e] = 0.f; accB[e] = 0.f; }
#pragma unroll
  for (int r = 0; r < 16; ++r) {
    const f16x8 hA = *(const f16x8*)(Eb + (size_t)r * SS + cA);
    const f16x8 hB = *(const f16x8*)(Eb + (size_t)r * SS + cB);
#pragma unroll
    for (int e = 0; e < 8; ++e) { accA[e] += eur[r] * (float)hA[e]; accB[e] += eur[r] * (float)hB[e]; }
  }
  float* co = colpart + ((size_t)b * NSTRIP + strip) * SS;
  *(f32x4*)&co[cA] = (f32x4){accA[0], accA[1], accA[2], accA[3]};
  *(f32x4*)&co[cA + 4] = (f32x4){accA[4], accA[5], accA[6], accA[7]};
  *(f32x4*)&co[cB] = (f32x4){accB[0], accB[1], accB[2], accB[3]};
  *(f32x4*)&co[cB + 4] = (f32x4){accB[4], accB[5], accB[6], accB[7]};
}

// ---------- reduce colpart -> ev_IT (+ sev atomic) ----------
template <int IT>
__global__ __launch_bounds__(256) void k_redcol(const float* __restrict__ colpart,
                                                float* __restrict__ evout,
                                                float* __restrict__ scal,
                                                const float* __restrict__ alpha_p) {
  __shared__ float red[4];
  const int b = blockIdx.y, t = threadIdx.x;
  const int c = blockIdx.x * 256 + t;
  const float alpha = *alpha_p;
  const float EA = __expf(alpha), HE = 0.5f * __expf(-alpha);
  const float enorm = 1.0f / 8192.0f;
  const float EU1BIN = HE / 4097.0f, BTV1 = 0.5f / 4097.0f;

  float s = 0.f;
  const float* cp = colpart + (size_t)b * NSTRIP * SS + c;
#pragma unroll 8
  for (int st = 0; st < NSTRIP; ++st) s += cp[(size_t)st * SS];

  float btv;
  if (IT == 1) {
    btv = BTV1;
  } else {
    const float sa1 = scal[b * 8 + 0];
    const float ev1bin = HE / (sa1 + EU1BIN);
    const float sev1 = scal[b * 8 + 1];
    const float eu2bin = HE / (sev1 + ev1bin);
    if (IT == 2) {
      btv = EA * eu2bin;
    } else {
      const float s2 = scal[b * 8 + 2];
      const float ev2bin = HE / (s2 + eu2bin);
      const float sev2 = scal[b * 8 + 3];
      const float eu3bin = HE / (sev2 + ev2bin);
      btv = EA * eu3bin;
    }
  }
  const float ev = enorm / (s + btv);
  evout[(size_t)b * SS + c] = ev;
  if (IT < 3) {
    const float bs = block_sum<4>(ev, red, t);
    if (t == 0) atomicAdd(&scal[b * 8 + (IT == 1 ? 1 : 3)], bs);
  }
}

// ---------- final: out = E * eu3[l] * ev3[s] * 8192 ----------
__global__ __launch_bounds__(256) void k_finalize(const f16* __restrict__ E,
                                                  float* __restrict__ out,
                                                  const float* __restrict__ eu3g,
                                                  const float* __restrict__ ev3g) {
  __shared__ float eu_s[16];
  const int b = blockIdx.y, rb = blockIdx.x;
  const int t = threadIdx.x, lane = t & 63, wave = t >> 6;
  if (t < 16) eu_s[t] = eu3g[(size_t)b * LL + rb * 16 + t] * 8192.0f;

  const float* evb = ev3g + (size_t)b * SS;
  f32x4 evr[16];
#pragma unroll
  for (int it = 0; it < 8; ++it) {
    const int base = (it * 64 + lane) * 8;
    evr[it * 2] = *(const f32x4*)&evb[base];
    evr[it * 2 + 1] = *(const f32x4*)&evb[base + 4];
  }
  __syncthreads();

  const size_t rbase = (size_t)b * LL * SS + (size_t)(rb * 16) * SS;
#pragma unroll
  for (int rr = 0; rr < 4; ++rr) {
    const int rloc = wave * 4 + rr;
    const float a = eu_s[rloc];
    const f16x8* rowp = (const f16x8*)(E + rbase + (size_t)rloc * SS);
    f32x4* orow = (f32x4*)(out + rbase + (size_t)rloc * SS);
#pragma unroll
    for (int it = 0; it < 8; ++it) {
      const f16x8 h = rowp[it * 64 + lane];
      f32x4 o0, o1;
#pragma unroll
      for (int e = 0; e < 4; ++e) o0[e] = (float)h[e] * a * evr[it * 2][e];
#pragma unroll
      for (int e = 0; e < 4; ++e) o1[e] = (float)h[4 + e] * a * evr[it * 2 + 1][e];
      orow[2 * (it * 64 + lane)] = o0;
      orow[2 * (it * 64 + lane) + 1] = o1;
    }
  }
}

// ---------- launch ----------
extern "C" void kernel_launch(void* const* d_in, const int* in_sizes, int n_in,
                              void* d_out, int out_size, void* d_ws, size_t ws_size,
                              hipStream_t stream) {
  const float* f0 = (const float*)d_in[0];
  const float* f1 = (const float*)d_in[1];
  const float* alpha_p = (const float*)d_in[2];
  float* out = (float*)d_out;

  char* ws = (char*)d_ws;
  size_t off = (size_t)NB * LL * SS * 2;                    // E: 128 MiB
  f16* E = (f16*)ws;
  u16* b0 = (u16*)(ws + off);      off += (size_t)NB * LL * CC * 2;
  u16* b1 = (u16*)(ws + off);      off += (size_t)NB * SS * CC * 2;
  float* rowpart = (float*)(ws + off); off += (size_t)NB * 64 * LL * 4;     // 4 MiB
  float* colpart = (float*)(ws + off); off += (size_t)NB * NSTRIP * SS * 4; // 16 MiB
  float* eu1g = (float*)(ws + off);    off += (size_t)NB * LL * 4;
  float* eu3g = (float*)(ws + off);    off += (size_t)NB * LL * 4;
  float* ev1g = (float*)(ws + off);    off += (size_t)NB * SS * 4;
  float* ev2g = (float*)(ws + off);    off += (size_t)NB * SS * 4;
  float* ev3g = (float*)(ws + off);    off += (size_t)NB * SS * 4;
  float* scal = (float*)(ws + off);    off += 256;

  hipMemsetAsync(scal, 0, 256, stream);                     // only the scalar accumulators

  k_convert<<<2048, 256, 0, stream>>>(f0, f1, b0, b1);
  k_gemm<<<dim3(SS / 128, LL / 128, NB), 256, 0, stream>>>(b0, b1, E, rowpart);
  k_redrow<<<NB, 1024, 0, stream>>>(rowpart, eu1g, scal, alpha_p);

  k_colpass<1><<<dim3(NSTRIP, NB), 256, 0, stream>>>(E, eu1g, nullptr, colpart, eu3g, scal, alpha_p);
  k_redcol<1><<<dim3(16, NB), 256, 0, stream>>>(colpart, ev1g, scal, alpha_p);

  k_colpass<2><<<dim3(NSTRIP, NB), 256, 0, stream>>>(E, eu1g, ev1g, colpart, eu3g, scal, alpha_p);
  k_redcol<2><<<dim3(16, NB), 256, 0, stream>>>(colpart, ev2g, scal, alpha_p);

  k_colpass<3><<<dim3(NSTRIP, NB), 256, 0, stream>>>(E, eu1g, ev2g, colpart, eu3g, scal, alpha_p);
  k_redcol<3><<<dim3(16, NB), 256, 0, stream>>>(colpart, ev3g, scal, alpha_p);

  k_finalize<<<dim3(LL / 16, NB), 256, 0, stream>>>(E, out, eu3g, ev3g);
}

// Round 8
// 295.490 us; speedup vs baseline: 4.2847x; 1.0275x over previous
//
#include <hip/hip_runtime.h>
#include <hip/hip_bf16.h>
#include <hip/hip_fp16.h>

#define NB 4
#define LL 4096
#define SS 4096
#define CC 128
#define NSTRIP 256   // LL / 16

typedef unsigned short u16;
typedef _Float16 f16;
typedef __attribute__((ext_vector_type(8))) short  short8;
typedef __attribute__((ext_vector_type(8))) f16    f16x8;
typedef __attribute__((ext_vector_type(4))) float  f32x4;
typedef __attribute__((ext_vector_type(4))) u16    u16x4;

// ---------- helpers ----------
__device__ __forceinline__ u16 f2bf(float f) {
  unsigned u = __float_as_uint(f);
  return (u16)((u + 0x7FFFu + ((u >> 16) & 1u)) >> 16);   // RNE, inputs finite
}

__device__ __forceinline__ void gload_lds16(const void* g, void* l) {
  __builtin_amdgcn_global_load_lds(
      (const __attribute__((address_space(1))) unsigned*)g,
      (__attribute__((address_space(3))) unsigned*)l, 16, 0, 0);
}

template <int NW>
__device__ __forceinline__ float block_sum(float v, float* red, int t) {
#pragma unroll
  for (int m = 1; m < 64; m <<= 1) v += __shfl_xor(v, m, 64);
  if ((t & 63) == 0) red[t >> 6] = v;
  __syncthreads();
  float s = 0.f;
#pragma unroll
  for (int w = 0; w < NW; ++w) s += red[w];
  __syncthreads();
  return s;
}

// ---------- fp32 -> bf16 conversion ----------
__global__ __launch_bounds__(256) void k_convert(const float* __restrict__ f0,
                                                 const float* __restrict__ f1,
                                                 u16* __restrict__ b0,
                                                 u16* __restrict__ b1) {
  const int i = blockIdx.x * 256 + threadIdx.x;
  const int n = NB * LL * CC / 4;
  if (i >= n) return;
  f32x4 x = ((const f32x4*)f0)[i];
  f32x4 y = ((const f32x4*)f1)[i];
  u16x4 a, c;
  a[0] = f2bf(x[0]); a[1] = f2bf(x[1]); a[2] = f2bf(x[2]); a[3] = f2bf(x[3]);
  c[0] = f2bf(y[0]); c[1] = f2bf(y[1]); c[2] = f2bf(y[2]); c[3] = f2bf(y[3]);
  ((u16x4*)b0)[i] = a;
  ((u16x4*)b1)[i] = c;
}

// ---------- bf16 MFMA GEMM: E = exp(f0.f1^T/128) f16, partial rowsums (no atomics) ----------
__global__ __launch_bounds__(256) void k_gemm(const u16* __restrict__ b0,
                                              const u16* __restrict__ b1,
                                              f16* __restrict__ E,
                                              float* __restrict__ rowpart) {
  __shared__ u16 smem[2 * 128 * 128];
  u16* lA = smem;
  u16* lB = smem + 128 * 128;
  const int bx = blockIdx.x, by = blockIdx.y, bz = blockIdx.z;
  const int tid = threadIdx.x;
  const int lane = tid & 63, wave = tid >> 6;

  const u16* gA = b0 + (size_t)bz * LL * CC + (size_t)by * 128 * CC;
  const u16* gB = b1 + (size_t)bz * SS * CC + (size_t)bx * 128 * CC;

#pragma unroll
  for (int i = 0; i < 8; ++i) {
    const int c = i * 256 + tid;
    const int row = c >> 4;
    const int slot = c & 15;
    const int kchunk = slot ^ (row & 7);
    const size_t soff = (size_t)row * CC + kchunk * 8;
    const int ldsoff = (i * 256 + wave * 64) * 16;
    gload_lds16(gA + soff, (char*)lA + ldsoff);
    gload_lds16(gB + soff, (char*)lB + ldsoff);
  }
  __syncthreads();

  const int wr = wave >> 1, wc = wave & 1;
  f32x4 acc[4][4];
#pragma unroll
  for (int i = 0; i < 4; ++i)
#pragma unroll
    for (int j = 0; j < 4; ++j) acc[i][j] = (f32x4){0.f, 0.f, 0.f, 0.f};

#pragma unroll
  for (int ks = 0; ks < 4; ++ks) {
    short8 af[4], bfr[4];
#pragma unroll
    for (int mi = 0; mi < 4; ++mi) {
      const int row = wr * 64 + mi * 16 + (lane & 15);
      const int kc = ks * 4 + (lane >> 4);
      af[mi] = *(const short8*)&lA[row * 128 + (kc ^ (row & 7)) * 8];
    }
#pragma unroll
    for (int ni = 0; ni < 4; ++ni) {
      const int row = wc * 64 + ni * 16 + (lane & 15);
      const int kc = ks * 4 + (lane >> 4);
      bfr[ni] = *(const short8*)&lB[row * 128 + (kc ^ (row & 7)) * 8];
    }
#pragma unroll
    for (int mi = 0; mi < 4; ++mi)
#pragma unroll
      for (int ni = 0; ni < 4; ++ni)
        acc[mi][ni] = __builtin_amdgcn_mfma_f32_16x16x32_bf16(af[mi], bfr[ni], acc[mi][ni], 0, 0, 0);
  }

  __syncthreads();                       // all LDS fragment reads done
  f16* st = (f16*)smem;                  // staging, row stride 136 f16 (16B-aligned rows)
  const float scale = 1.0f / 128.0f;
  // rowpart slice: [bz][bx*2+wc][row]  (each wave's 64-col half-sum, no races)
  float* rp = rowpart + ((size_t)bz * 64 + bx * 2 + wc) * LL + by * 128;
#pragma unroll
  for (int mi = 0; mi < 4; ++mi) {
    float rs[4] = {0.f, 0.f, 0.f, 0.f};
    const int lr0 = wr * 64 + mi * 16 + (lane >> 4) * 4;
#pragma unroll
    for (int ni = 0; ni < 4; ++ni) {
      const int lc = wc * 64 + ni * 16 + (lane & 15);
      f32x4 a = acc[mi][ni];
#pragma unroll
      for (int r = 0; r < 4; ++r) {
        const f16 eh = (f16)__expf(a[r] * scale);
        st[(lr0 + r) * 136 + lc] = eh;
        rs[r] += (float)eh;
      }
    }
#pragma unroll
    for (int m = 1; m < 16; m <<= 1)
#pragma unroll
      for (int r = 0; r < 4; ++r) rs[r] += __shfl_xor(rs[r], m, 64);
    if ((lane & 15) == 0) {
#pragma unroll
      for (int r = 0; r < 4; ++r) rp[lr0 + r] = rs[r];
    }
  }
  __syncthreads();
  const size_t ebase = (size_t)bz * LL * SS + (size_t)(by * 128) * SS + (size_t)(bx * 128);
#pragma unroll
  for (int i = 0; i < 8; ++i) {
    const int c = i * 256 + tid;
    const int row = c >> 4, c16 = c & 15;
    f16x8 vv = *(const f16x8*)&st[row * 136 + c16 * 8];
    *(f16x8*)&E[ebase + (size_t)row * SS + c16 * 8] = vv;
  }
}

// ---------- reduce rowpart -> eu1, sa1 (64 blocks, coalesced) ----------
__global__ __launch_bounds__(256) void k_redrow(const float* __restrict__ rowpart,
                                                float* __restrict__ eu1g,
                                                float* __restrict__ scal,
                                                const float* __restrict__ alpha_p) {
  __shared__ float red[4];
  const int b = blockIdx.y, t = threadIdx.x;
  const int l = blockIdx.x * 256 + t;
  const float EA = __expf(*alpha_p);
  const float enorm = 1.0f / 8192.0f;
  float s = 0.f;
  const float* rp = rowpart + (size_t)b * 64 * LL + l;
#pragma unroll 8
  for (int j = 0; j < 64; ++j) s += rp[(size_t)j * LL];
  const float eu = enorm / (s + EA);
  eu1g[(size_t)b * LL + l] = eu;
  const float bs = block_sum<4>(eu, red, t);
  if (t == 0) atomicAdd(&scal[b * 8 + 0], bs);
}

// ---------- column pass IT=1..3: (IT>1: row-dots -> eu), colpart[strip] = sum(eu*E)
//            IT>1 holds the 16x16 E sub-strip in registers: ONE E read total ----------
template <int IT>
__global__ __launch_bounds__(256, 2) void k_colpass(const f16* __restrict__ E,
                                                    const float* __restrict__ eu1g,
                                                    const float* __restrict__ evprev,
                                                    float* __restrict__ colpart,
                                                    float* __restrict__ eu3g,
                                                    float* __restrict__ scal,
                                                    const float* __restrict__ alpha_p) {
  __shared__ float lds_red[4][16];
  __shared__ float eu_lds[16];
  const int b = blockIdx.y, strip = blockIdx.x;
  const int t = threadIdx.x, lane = t & 63, wave = t >> 6;
  const float alpha = *alpha_p;
  const float EA = __expf(alpha), HE = 0.5f * __expf(-alpha);
  const float enorm = 1.0f / 8192.0f;
  const float EU1BIN = HE / 4097.0f;

  const f16* Eb = E + (size_t)b * LL * SS + (size_t)strip * 16 * SS;
  const int cA = t * 8, cB = 2048 + t * 8;
  float* co = colpart + ((size_t)b * NSTRIP + strip) * SS;

  if (IT == 1) {
    // single streaming pass with eu1 from redrow
    const float* e1 = eu1g + (size_t)b * LL + strip * 16;
    float eur[16];
#pragma unroll
    for (int r = 0; r < 16; ++r) eur[r] = e1[r];
    float accA[8], accB[8];
#pragma unroll
    for (int e = 0; e < 8; ++e) { accA[e] = 0.f; accB[e] = 0.f; }
#pragma unroll
    for (int r = 0; r < 16; ++r) {
      const f16x8 hA = *(const f16x8*)(Eb + (size_t)r * SS + cA);
      const f16x8 hB = *(const f16x8*)(Eb + (size_t)r * SS + cB);
#pragma unroll
      for (int e = 0; e < 8; ++e) { accA[e] += eur[r] * (float)hA[e]; accB[e] += eur[r] * (float)hB[e]; }
    }
    *(f32x4*)&co[cA] = (f32x4){accA[0], accA[1], accA[2], accA[3]};
    *(f32x4*)&co[cA + 4] = (f32x4){accA[4], accA[5], accA[6], accA[7]};
    *(f32x4*)&co[cB] = (f32x4){accB[0], accB[1], accB[2], accB[3]};
    *(f32x4*)&co[cB + 4] = (f32x4){accB[4], accB[5], accB[6], accB[7]};
    return;
  }

  // ---- IT >= 2: bin-chain scalars ----
  const float sa1 = scal[b * 8 + 0];
  const float ev1bin = HE / (sa1 + EU1BIN);
  float btu;
  if (IT == 2) {
    btu = EA * ev1bin;
  } else {
    const float sev1 = scal[b * 8 + 1];
    const float eu2bin = HE / (sev1 + ev1bin);
    const float s2 = scal[b * 8 + 2];
    const float ev2bin = HE / (s2 + eu2bin);
    btu = EA * ev2bin;
  }
  const float* evb = evprev + (size_t)b * SS;
  const f32x4 evA0 = *(const f32x4*)&evb[cA];
  const f32x4 evA1 = *(const f32x4*)&evb[cA + 4];
  const f32x4 evB0 = *(const f32x4*)&evb[cB];
  const f32x4 evB1 = *(const f32x4*)&evb[cB + 4];

  // phase A: load E sub-strip into registers + per-thread partial row-dots
  f16x8 eAr[16], eBr[16];
  float partial[16];
#pragma unroll
  for (int r = 0; r < 16; ++r) {
    eAr[r] = *(const f16x8*)(Eb + (size_t)r * SS + cA);
    eBr[r] = *(const f16x8*)(Eb + (size_t)r * SS + cB);
    float d = 0.f;
#pragma unroll
    for (int e = 0; e < 4; ++e) d += (float)eAr[r][e] * evA0[e];
#pragma unroll
    for (int e = 0; e < 4; ++e) d += (float)eAr[r][4 + e] * evA1[e];
#pragma unroll
    for (int e = 0; e < 4; ++e) d += (float)eBr[r][e] * evB0[e];
#pragma unroll
    for (int e = 0; e < 4; ++e) d += (float)eBr[r][4 + e] * evB1[e];
    partial[r] = d;
  }

  // phase B: block reduction of 16 row-dots
#pragma unroll
  for (int m = 1; m < 64; m <<= 1)
#pragma unroll
    for (int r = 0; r < 16; ++r) partial[r] += __shfl_xor(partial[r], m, 64);
  if (lane == 0) {
#pragma unroll
    for (int r = 0; r < 16; ++r) lds_red[wave][r] = partial[r];
  }
  __syncthreads();
  if (t < 16) {
    const float rd = lds_red[0][t] + lds_red[1][t] + lds_red[2][t] + lds_red[3][t];
    const float eu = enorm / (rd + btu);
    eu_lds[t] = eu;
    if (IT == 3) eu3g[(size_t)b * LL + strip * 16 + t] = eu;
  }
  __syncthreads();
  if (IT == 2 && t == 0) {
    float s = 0.f;
#pragma unroll
    for (int r = 0; r < 16; ++r) s += eu_lds[r];
    atomicAdd(&scal[b * 8 + 2], s);
  }
  float eur[16];
#pragma unroll
  for (int r = 0; r < 16; ++r) eur[r] = eu_lds[r];

  // phase C: colpart from REGISTER-held E (no second memory read)
  float accA[8], accB[8];
#pragma unroll
  for (int e = 0; e < 8; ++e) { accA[e] = 0.f; accB[e] = 0.f; }
#pragma unroll
  for (int r = 0; r < 16; ++r) {
#pragma unroll
    for (int e = 0; e < 8; ++e) { accA[e] += eur[r] * (float)eAr[r][e]; accB[e] += eur[r] * (float)eBr[r][e]; }
  }
  *(f32x4*)&co[cA] = (f32x4){accA[0], accA[1], accA[2], accA[3]};
  *(f32x4*)&co[cA + 4] = (f32x4){accA[4], accA[5], accA[6], accA[7]};
  *(f32x4*)&co[cB] = (f32x4){accB[0], accB[1], accB[2], accB[3]};
  *(f32x4*)&co[cB + 4] = (f32x4){accB[4], accB[5], accB[6], accB[7]};
}

// ---------- reduce colpart -> ev_IT (+ sev atomic) ----------
template <int IT>
__global__ __launch_bounds__(256) void k_redcol(const float* __restrict__ colpart,
                                                float* __restrict__ evout,
                                                float* __restrict__ scal,
                                                const float* __restrict__ alpha_p) {
  __shared__ float red[4];
  const int b = blockIdx.y, t = threadIdx.x;
  const int c = blockIdx.x * 256 + t;
  const float alpha = *alpha_p;
  const float EA = __expf(alpha), HE = 0.5f * __expf(-alpha);
  const float enorm = 1.0f / 8192.0f;
  const float EU1BIN = HE / 4097.0f, BTV1 = 0.5f / 4097.0f;

  float s = 0.f;
  const float* cp = colpart + (size_t)b * NSTRIP * SS + c;
#pragma unroll 8
  for (int st = 0; st < NSTRIP; ++st) s += cp[(size_t)st * SS];

  float btv;
  if (IT == 1) {
    btv = BTV1;
  } else {
    const float sa1 = scal[b * 8 + 0];
    const float ev1bin = HE / (sa1 + EU1BIN);
    const float sev1 = scal[b * 8 + 1];
    const float eu2bin = HE / (sev1 + ev1bin);
    if (IT == 2) {
      btv = EA * eu2bin;
    } else {
      const float s2 = scal[b * 8 + 2];
      const float ev2bin = HE / (s2 + eu2bin);
      const float sev2 = scal[b * 8 + 3];
      const float eu3bin = HE / (sev2 + ev2bin);
      btv = EA * eu3bin;
    }
  }
  const float ev = enorm / (s + btv);
  evout[(size_t)b * SS + c] = ev;
  if (IT < 3) {
    const float bs = block_sum<4>(ev, red, t);
    if (t == 0) atomicAdd(&scal[b * 8 + (IT == 1 ? 1 : 3)], bs);
  }
}

// ---------- final: out = E * eu3[l] * ev3[s] * 8192 ----------
__global__ __launch_bounds__(256) void k_finalize(const f16* __restrict__ E,
                                                  float* __restrict__ out,
                                                  const float* __restrict__ eu3g,
                                                  const float* __restrict__ ev3g) {
  __shared__ float eu_s[16];
  const int b = blockIdx.y, rb = blockIdx.x;
  const int t = threadIdx.x, lane = t & 63, wave = t >> 6;
  if (t < 16) eu_s[t] = eu3g[(size_t)b * LL + rb * 16 + t] * 8192.0f;

  const float* evb = ev3g + (size_t)b * SS;
  f32x4 evr[16];
#pragma unroll
  for (int it = 0; it < 8; ++it) {
    const int base = (it * 64 + lane) * 8;
    evr[it * 2] = *(const f32x4*)&evb[base];
    evr[it * 2 + 1] = *(const f32x4*)&evb[base + 4];
  }
  __syncthreads();

  const size_t rbase = (size_t)b * LL * SS + (size_t)(rb * 16) * SS;
#pragma unroll
  for (int rr = 0; rr < 4; ++rr) {
    const int rloc = wave * 4 + rr;
    const float a = eu_s[rloc];
    const f16x8* rowp = (const f16x8*)(E + rbase + (size_t)rloc * SS);
    f32x4* orow = (f32x4*)(out + rbase + (size_t)rloc * SS);
#pragma unroll
    for (int it = 0; it < 8; ++it) {
      const f16x8 h = rowp[it * 64 + lane];
      f32x4 o0, o1;
#pragma unroll
      for (int e = 0; e < 4; ++e) o0[e] = (float)h[e] * a * evr[it * 2][e];
#pragma unroll
      for (int e = 0; e < 4; ++e) o1[e] = (float)h[4 + e] * a * evr[it * 2 + 1][e];
      orow[2 * (it * 64 + lane)] = o0;
      orow[2 * (it * 64 + lane) + 1] = o1;
    }
  }
}

// ---------- launch ----------
extern "C" void kernel_launch(void* const* d_in, const int* in_sizes, int n_in,
                              void* d_out, int out_size, void* d_ws, size_t ws_size,
                              hipStream_t stream) {
  const float* f0 = (const float*)d_in[0];
  const float* f1 = (const float*)d_in[1];
  const float* alpha_p = (const float*)d_in[2];
  float* out = (float*)d_out;

  char* ws = (char*)d_ws;
  size_t off = (size_t)NB * LL * SS * 2;                    // E: 128 MiB
  f16* E = (f16*)ws;
  u16* b0 = (u16*)(ws + off);      off += (size_t)NB * LL * CC * 2;
  u16* b1 = (u16*)(ws + off);      off += (size_t)NB * SS * CC * 2;
  float* rowpart = (float*)(ws + off); off += (size_t)NB * 64 * LL * 4;     // 4 MiB
  float* colpart = (float*)(ws + off); off += (size_t)NB * NSTRIP * SS * 4; // 16 MiB
  float* eu1g = (float*)(ws + off);    off += (size_t)NB * LL * 4;
  float* eu3g = (float*)(ws + off);    off += (size_t)NB * LL * 4;
  float* ev1g = (float*)(ws + off);    off += (size_t)NB * SS * 4;
  float* ev2g = (float*)(ws + off);    off += (size_t)NB * SS * 4;
  float* ev3g = (float*)(ws + off);    off += (size_t)NB * SS * 4;
  float* scal = (float*)(ws + off);    off += 256;

  hipMemsetAsync(scal, 0, 256, stream);                     // only the scalar accumulators

  k_convert<<<2048, 256, 0, stream>>>(f0, f1, b0, b1);
  k_gemm<<<dim3(SS / 128, LL / 128, NB), 256, 0, stream>>>(b0, b1, E, rowpart);
  k_redrow<<<dim3(16, NB), 256, 0, stream>>>(rowpart, eu1g, scal, alpha_p);

  k_colpass<1><<<dim3(NSTRIP, NB), 256, 0, stream>>>(E, eu1g, nullptr, colpart, eu3g, scal, alpha_p);
  k_redcol<1><<<dim3(16, NB), 256, 0, stream>>>(colpart, ev1g, scal, alpha_p);

  k_colpass<2><<<dim3(NSTRIP, NB), 256, 0, stream>>>(E, eu1g, ev1g, colpart, eu3g, scal, alpha_p);
  k_redcol<2><<<dim3(16, NB), 256, 0, stream>>>(colpart, ev2g, scal, alpha_p);

  k_colpass<3><<<dim3(NSTRIP, NB), 256, 0, stream>>>(E, eu1g, ev2g, colpart, eu3g, scal, alpha_p);
  k_redcol<3><<<dim3(16, NB), 256, 0, stream>>>(colpart, ev3g, scal, alpha_p);

  k_finalize<<<dim3(LL / 16, NB), 256, 0, stream>>>(E, out, eu3g, ev3g);
}